// Round 4
// baseline (151.113 us; speedup 1.0000x reference)
//
#include <hip/hip_runtime.h>
#include <stdint.h>

#define C_CH 192
#define HW   4096
#define NB   16
#define NO   5

typedef __attribute__((ext_vector_type(8)))  short short8;
typedef __attribute__((ext_vector_type(16))) float floatx16;

__device__ __forceinline__ unsigned short f2bf(float f) {
    unsigned int u = __float_as_uint(f);
    unsigned int r = (u + 0x7fffu + ((u >> 16) & 1u)) >> 16;  // RNE to bf16
    return (unsigned short)r;
}

__device__ __forceinline__ uint4 s8u4(short8 f) { return *(uint4*)&f; }

// shift fragment toward lower index: out[j] = {ex, f[0..6]}   (dx = -1)
__device__ __forceinline__ short8 shift_m(short8 f, unsigned short ex) {
    uint4 v = *(uint4*)&f; uint4 w;
    w.x = (unsigned)ex   | (v.x << 16);
    w.y = (v.x >> 16)    | (v.y << 16);
    w.z = (v.y >> 16)    | (v.z << 16);
    w.w = (v.z >> 16)    | (v.w << 16);
    return *(short8*)&w;
}
// shift toward higher index: out[j] = {f[1..7], ex}   (dx = +1)
__device__ __forceinline__ short8 shift_p(short8 f, unsigned short ex) {
    uint4 v = *(uint4*)&f; uint4 w;
    w.x = (v.x >> 16) | (v.y << 16);
    w.y = (v.y >> 16) | (v.z << 16);
    w.z = (v.z >> 16) | (v.w << 16);
    w.w = (v.w >> 16) | ((unsigned)ex << 16);
    return *(short8*)&w;
}

// Build shifted variants of the 16-elem k-step fragment held as Uarr[S] across the
// lo=0/lo=1 half-waves. Edge elements come from the partner lane (lane^32) via shfl,
// with w=0 / w=63 clamps at S==0 (lo=0) and S==3 (lo=1).
// R4 NOTE: this is the EXACT harness-verified R0 form (two __shfl_xor). R3's
// v_permlane32_swap_b32 replacement failed correctness (absmax 8.5e-3) — its
// half-swap lane convention was unverified; do not reintroduce without a
// standalone semantics probe.
#define MAKE_SHIFT(Uarr, S, Um, Up)                                              \
    do {                                                                         \
        uint4 _u0 = s8u4(Uarr[(S) > 0 ? (S) - 1 : 0]);                           \
        uint4 _u1 = s8u4(Uarr[S]);                                               \
        uint4 _u2 = s8u4(Uarr[(S) < 3 ? (S) + 1 : 3]);                           \
        unsigned _sm = lo ? _u0.w : _u1.w;                                       \
        unsigned _sp = lo ? _u1.x : _u2.x;                                       \
        unsigned _rm = (unsigned)__shfl_xor((int)_sm, 32, 64);                   \
        unsigned _rp = (unsigned)__shfl_xor((int)_sp, 32, 64);                   \
        unsigned short _exm = (unsigned short)(_rm >> 16);                       \
        if ((S) == 0) _exm = lo ? _exm : (unsigned short)(_u1.x & 0xffffu);      \
        unsigned short _exp = (unsigned short)(_rp & 0xffffu);                   \
        if ((S) == 3) _exp = lo ? (unsigned short)(_u1.w >> 16) : _exp;          \
        Um = shift_m(Uarr[S], _exm);                                             \
        Up = shift_p(Uarr[S], _exp);                                             \
    } while (0)

// ---------------- Kernel 1: fp32 -> bf16, fragment-tiled layout (verified R0) ----------------
// xb short8 index: grp*16384 + q*32 + c'    (grp = b*6+cb, q = k>>3, c' = ch&31)
__global__ __launch_bounds__(256) void convert_kernel(const float* __restrict__ x,
                                                      unsigned short* __restrict__ xb,
                                                      float* __restrict__ norms) {
    if (blockIdx.x == 0 && threadIdx.x < NB * NO) norms[threadIdx.x] = 0.0f;
    int t   = blockIdx.x * 256 + threadIdx.x;   // 1,572,864 threads
    int grp = t >> 14;                          // 96 groups of (b, cb)
    int idx = t & 16383;
    int qhi = idx >> 8;
    int cp  = (idx >> 3) & 31;
    int qlo = idx & 7;
    int q   = qhi * 8 + qlo;
    int b   = grp / 6;
    int cb  = grp - b * 6;
    int ch  = cb * 32 + cp;
    const float4* p = (const float4*)(x + (size_t)(b * C_CH + ch) * HW + q * 8);
    float4 v0 = p[0], v1 = p[1];
    ushort4 o0, o1;
    o0.x = f2bf(v0.x); o0.y = f2bf(v0.y); o0.z = f2bf(v0.z); o0.w = f2bf(v0.w);
    o1.x = f2bf(v1.x); o1.y = f2bf(v1.y); o1.z = f2bf(v1.z); o1.w = f2bf(v1.w);
    ushort4* dst = (ushort4*)xb + ((size_t)grp * 16384 + q * 32 + cp) * 2;
    dst[0] = o0; dst[1] = o1;
}

// ---------------- Kernel 2: fused 5-offset Gram, 64x32 tile, 4-wave blocks ----------------
// R4: grid 288 = 16 b x 3 cbA2 x 6 cbB. Each block computes a 64(chA) x 32(chB)
// Gram tile: TWO A-streams (cbA = 2*cbA2, 2*cbA2+1) share ONE B-stream and ONE
// shift computation -> 10 MFMAs per 3 loads per step (R0: 5 per 2). 256 threads
// = 4 waves; wave wv owns k-rows [16wv, 16wv+16). ~160 AGPR + ~150 VGPR ->
// deliberately 1 wave/SIMD (launch_bounds(256,1), <=512 regs, no spill): the
// doubled MFMA-per-rendezvous amortizes the per-step load/shift stall that R0's
// counters showed (770 cyc wall per 160 cyc of MFMA issue; MfmaUtil 19.6%).
// Offsets machinery identical to verified R0 (row pairing g/g+1 for dy=-1 with
// h=0 boundary and g=0..62 series; in-fragment shift for dx=+-1).
__global__ __launch_bounds__(256, 1) void cofe_gemm(const unsigned short* __restrict__ xb,
                                                    float* __restrict__ out,
                                                    float* __restrict__ norms) {
    constexpr int RW = 16;
    int blk  = blockIdx.x;
    int work = (blk & 7) * 36 + (blk >> 3);     // XCD swizzle: contiguous work per XCD
    int b = work / 18;
    int t = work % 18;
    int cbA2 = t / 6, cbB = t % 6;
    int d0 = cbB * 32;

    int wv   = threadIdx.x >> 6;                // 0..3
    int lane = threadIdx.x & 63;
    int lr   = lane & 31;
    int lo   = lane >> 5;
    int laneoff = lo * 32 + lr;                 // short8 units

    const short8* A8a = (const short8*)xb + (size_t)(b * 6 + cbA2 * 2) * 16384;
    const short8* A8b = A8a + 16384;
    const short8* B8  = (const short8*)xb + (size_t)(b * 6 + cbB) * 16384;

    floatx16 acc_a[5], acc_b[5];
    #pragma unroll
    for (int o = 0; o < 5; ++o)
        #pragma unroll
        for (int e = 0; e < 16; ++e) { acc_a[o][e] = 0.0f; acc_b[o][e] = 0.0f; }

    int h0 = wv * RW;

    short8 U[2][4];     // B rows: ping-pong
    short8 Aa[3][4];    // A stream 0: rotate (g, g+1, g+2)
    short8 Ab[3][4];    // A stream 1

    #pragma unroll
    for (int s = 0; s < 4; ++s) {
        U[0][s]  = B8 [(8 * h0 + 2 * s) * 32 + laneoff];
        Aa[0][s] = A8a[(8 * h0 + 2 * s) * 32 + laneoff];
        Ab[0][s] = A8b[(8 * h0 + 2 * s) * 32 + laneoff];
        Aa[1][s] = A8a[(8 * (h0 + 1) + 2 * s) * 32 + laneoff];
        Ab[1][s] = A8b[(8 * (h0 + 1) + 2 * s) * 32 + laneoff];
    }

    // h = 0 boundary: dy=-1 offsets pair center row 0 with clamped side row 0
    if (h0 == 0) {
        #pragma unroll
        for (int s = 0; s < 4; ++s) {
            short8 Um, Up;
            MAKE_SHIFT(U[0], s, Um, Up);
            acc_a[0] = __builtin_amdgcn_mfma_f32_32x32x16_bf16(Aa[0][s], Um,      acc_a[0], 0, 0, 0);
            acc_a[1] = __builtin_amdgcn_mfma_f32_32x32x16_bf16(Aa[0][s], U[0][s], acc_a[1], 0, 0, 0);
            acc_a[2] = __builtin_amdgcn_mfma_f32_32x32x16_bf16(Aa[0][s], Up,      acc_a[2], 0, 0, 0);
            acc_b[0] = __builtin_amdgcn_mfma_f32_32x32x16_bf16(Ab[0][s], Um,      acc_b[0], 0, 0, 0);
            acc_b[1] = __builtin_amdgcn_mfma_f32_32x32x16_bf16(Ab[0][s], U[0][s], acc_b[1], 0, 0, 0);
            acc_b[2] = __builtin_amdgcn_mfma_f32_32x32x16_bf16(Ab[0][s], Up,      acc_b[2], 0, 0, 0);
        }
    }

    #pragma unroll
    for (int r = 0; r < RW; ++r) {
        int g  = h0 + r;
        const int cu = r & 1, nx = (r + 1) & 1;
        const int ia = r % 3, ib = (r + 1) % 3, ic = (r + 2) % 3;
        int ga = (g + 2 < 64) ? g + 2 : 63;     // A prefetch row (clamped dummy at tail)
        int gu = (g + 1 < 64) ? g + 1 : 63;     // B prefetch row
        #pragma unroll
        for (int s = 0; s < 4; ++s) {
            Aa[ic][s] = A8a[(8 * ga + 2 * s) * 32 + laneoff];
            Ab[ic][s] = A8b[(8 * ga + 2 * s) * 32 + laneoff];
            U[nx][s]  = B8 [(8 * gu + 2 * s) * 32 + laneoff];

            short8 Um, Up;
            MAKE_SHIFT(U[cu], s, Um, Up);

            // OFFSETS: 0:(-1,-1) 1:(-1,0) 2:(-1,1) 3:(0,-1) 4:(0,0)
            acc_a[4] = __builtin_amdgcn_mfma_f32_32x32x16_bf16(Aa[ia][s], U[cu][s], acc_a[4], 0, 0, 0);
            acc_b[4] = __builtin_amdgcn_mfma_f32_32x32x16_bf16(Ab[ia][s], U[cu][s], acc_b[4], 0, 0, 0);
            acc_a[3] = __builtin_amdgcn_mfma_f32_32x32x16_bf16(Aa[ia][s], Um,       acc_a[3], 0, 0, 0);
            acc_b[3] = __builtin_amdgcn_mfma_f32_32x32x16_bf16(Ab[ia][s], Um,       acc_b[3], 0, 0, 0);
            if (r + 1 < RW || g < 63) {         // dy=-1 sum runs g = 0..62
                acc_a[1] = __builtin_amdgcn_mfma_f32_32x32x16_bf16(Aa[ib][s], U[cu][s], acc_a[1], 0, 0, 0);
                acc_b[1] = __builtin_amdgcn_mfma_f32_32x32x16_bf16(Ab[ib][s], U[cu][s], acc_b[1], 0, 0, 0);
                acc_a[0] = __builtin_amdgcn_mfma_f32_32x32x16_bf16(Aa[ib][s], Um,       acc_a[0], 0, 0, 0);
                acc_b[0] = __builtin_amdgcn_mfma_f32_32x32x16_bf16(Ab[ib][s], Um,       acc_b[0], 0, 0, 0);
                acc_a[2] = __builtin_amdgcn_mfma_f32_32x32x16_bf16(Aa[ib][s], Up,       acc_a[2], 0, 0, 0);
                acc_b[2] = __builtin_amdgcn_mfma_f32_32x32x16_bf16(Ab[ib][s], Up,       acc_b[2], 0, 0, 0);
            }
        }
    }

    // ---- epilogue: LDS-reduce 4 wave partials, store, one norm atomic per offset ----
    __shared__ float red[4096];   // 16 KB
    __shared__ float wsum[4];
    float4* red4 = (float4*)red;
    size_t obase = (size_t)b * NO * (C_CH * C_CH);
    int tt = threadIdx.x;

#define EPILOGUE(ACC, C0)                                                        \
    for (int o = 0; o < 5; ++o) {                                                \
        __syncthreads();                                                         \
        _Pragma("unroll")                                                        \
        for (int reg = 0; reg < 16; ++reg) {                                     \
            int row_ = (reg & 3) + 8 * (reg >> 2) + 4 * lo;  /* C/D layout */    \
            red[wv * 1024 + row_ * 32 + lr] = ACC[o][reg];                       \
        }                                                                        \
        __syncthreads();                                                         \
        float4 sv = red4[tt];                                                    \
        _Pragma("unroll")                                                        \
        for (int seg = 1; seg < 4; ++seg) {                                      \
            float4 v = red4[seg * 256 + tt];                                     \
            sv.x += v.x; sv.y += v.y; sv.z += v.z; sv.w += v.w;                  \
        }                                                                        \
        int row_ = tt >> 3;                                                      \
        int col_ = (tt & 7) * 4;                                                 \
        float* op = out + obase + (size_t)o * (C_CH * C_CH)                      \
                  + (size_t)((C0) + row_) * C_CH + d0 + col_;                    \
        *(float4*)op = sv;                                                       \
        float ss = sv.x * sv.x + sv.y * sv.y + sv.z * sv.z + sv.w * sv.w;        \
        _Pragma("unroll")                                                        \
        for (int off = 32; off; off >>= 1) ss += __shfl_down(ss, off, 64);       \
        if (lane == 0) wsum[wv] = ss;                                            \
        __syncthreads();                                                         \
        if (tt == 0) atomicAdd(&norms[b * NO + o],                               \
                               wsum[0] + wsum[1] + wsum[2] + wsum[3]);           \
    }

    EPILOGUE(acc_a, cbA2 * 64)
    EPILOGUE(acc_b, cbA2 * 64 + 32)
#undef EPILOGUE
}

// ---------------- Kernel 3: scale by 1/norm ----------------
__global__ __launch_bounds__(256) void scale_kernel(float* __restrict__ out,
                                                    const float* __restrict__ norms) {
    int g  = blockIdx.x * 256 + threadIdx.x;    // float4 index, 737,280 total
    int bo = blockIdx.x / 36;                   // 9216 float4 per (b,o)
    float s = norms[bo];
    float inv = 1.0f / fmaxf(sqrtf(s), 1e-12f);
    float4 v = ((const float4*)out)[g];
    v.x *= inv; v.y *= inv; v.z *= inv; v.w *= inv;
    ((float4*)out)[g] = v;
}

extern "C" void kernel_launch(void* const* d_in, const int* in_sizes, int n_in,
                              void* d_out, int out_size, void* d_ws, size_t ws_size,
                              hipStream_t stream) {
    const float* x = (const float*)d_in[0];
    float* out = (float*)d_out;
    float* norms = (float*)d_ws;                                   // 80 floats (+pad)
    unsigned short* xb = (unsigned short*)((char*)d_ws + 512);     // 25,165,824 B bf16 tiled

    convert_kernel<<<6144, 256, 0, stream>>>(x, xb, norms);
    cofe_gemm<<<288, 256, 0, stream>>>(xb, out, norms);
    scale_kernel<<<2880, 256, 0, stream>>>(out, norms);
}

// Round 5
// 148.952 us; speedup vs baseline: 1.0145x; 1.0145x over previous
//
#include <hip/hip_runtime.h>
#include <stdint.h>

#define C_CH 192
#define HW   4096
#define NB   16
#define NO   5
#define PANEL 25165824   // bytes per bf16 panel: 96 grp * 16384 octets * 16 B

typedef __attribute__((ext_vector_type(8)))  short short8;
typedef __attribute__((ext_vector_type(16))) float floatx16;

__device__ __forceinline__ unsigned short f2bf(float f) {
    unsigned int u = __float_as_uint(f);
    unsigned int r = (u + 0x7fffu + ((u >> 16) & 1u)) >> 16;  // RNE to bf16
    return (unsigned short)r;
}

// ---------------- Kernel 1: fp32 -> bf16, fragment-tiled, 3 pre-shifted panels ----------------
// xb octet index: grp*16384 + q*32 + c'   (grp = b*6+cb, q = k>>3, c' = ch&31)
// k = h*64 + w; octet q covers one h, w = 8*(q&7)..8*(q&7)+7. Lanes t&7 = q&7 cover
// the 8 w-octets of one h-row -> w-shifts are lane-neighbor exchanges here (free in
// this memory-bound kernel), R0-verified clamp semantics:
//   Um[w] = B[max(w-1,0)]  (clamp at w=0:  own e0)
//   Up[w] = B[min(w+1,63)] (clamp at w=63: own e7)
// R5: shifts PRECOMPUTED here so cofe_gemm's hot loop has no shfl/shift chain
// (R0 counters: ~770 cyc/step wall vs 160 cyc MFMA issue; chain was the stall).
__global__ __launch_bounds__(256) void convert_kernel(const float* __restrict__ x,
                                                      unsigned short* __restrict__ xb,
                                                      unsigned short* __restrict__ xbm,
                                                      unsigned short* __restrict__ xbp,
                                                      float* __restrict__ norms) {
    if (blockIdx.x == 0 && threadIdx.x < NB * NO) norms[threadIdx.x] = 0.0f;
    int t   = blockIdx.x * 256 + threadIdx.x;   // 1,572,864 threads
    int grp = t >> 14;                          // 96 groups of (b, cb)
    int idx = t & 16383;
    int qhi = idx >> 8;
    int cp  = (idx >> 3) & 31;
    int qlo = idx & 7;
    int q   = qhi * 8 + qlo;
    int b   = grp / 6;
    int cb  = grp - b * 6;
    int ch  = cb * 32 + cp;
    const float4* p = (const float4*)(x + (size_t)(b * C_CH + ch) * HW + q * 8);
    float4 v0 = p[0], v1 = p[1];
    unsigned u0 = (unsigned)f2bf(v0.x) | ((unsigned)f2bf(v0.y) << 16);
    unsigned u1 = (unsigned)f2bf(v0.z) | ((unsigned)f2bf(v0.w) << 16);
    unsigned u2 = (unsigned)f2bf(v1.x) | ((unsigned)f2bf(v1.y) << 16);
    unsigned u3 = (unsigned)f2bf(v1.z) | ((unsigned)f2bf(v1.w) << 16);

    // neighbor w-octet elements (lane +-1 within the 8-lane q-group)
    unsigned prev_u3 = (unsigned)__shfl_up((int)u3, 1, 64);    // lane-1's e6e7
    unsigned next_u0 = (unsigned)__shfl_down((int)u0, 1, 64);  // lane+1's e0e1
    unsigned short exm = (qlo == 0) ? (unsigned short)(u0 & 0xffffu)
                                    : (unsigned short)(prev_u3 >> 16);
    unsigned short exp_ = (qlo == 7) ? (unsigned short)(u3 >> 16)
                                     : (unsigned short)(next_u0 & 0xffffu);

    uint4 cen = {u0, u1, u2, u3};
    uint4 um, up;
    um.x = (unsigned)exm | (u0 << 16);          // shift toward lower w
    um.y = (u0 >> 16)    | (u1 << 16);
    um.z = (u1 >> 16)    | (u2 << 16);
    um.w = (u2 >> 16)    | (u3 << 16);
    up.x = (u0 >> 16)    | (u1 << 16);          // shift toward higher w
    up.y = (u1 >> 16)    | (u2 << 16);
    up.z = (u2 >> 16)    | (u3 << 16);
    up.w = (u3 >> 16)    | ((unsigned)exp_ << 16);

    size_t oct = (size_t)grp * 16384 + q * 32 + cp;
    ((uint4*)xb)[oct]  = cen;
    ((uint4*)xbm)[oct] = um;
    ((uint4*)xbp)[oct] = up;
}

// ---------------- Kernel 2: fused 5-offset Gram, pure load->MFMA stream ----------------
// R5: grid 576 = 16 b x 36 (32x32)-tiles; 256 threads = 4 waves; wave wv owns
// k-rows [16wv, 16wv+16). No cross-lane ops in the loop: the three B-variants
// (U, Um, Up) are separate pre-shifted panels, loaded with 1-row prefetch
// (ping-pong) alongside the A rotate-3 stream. Per s-step: 4 loads, 5 MFMAs.
// Row-pairing algebra identical to verified R0/R4 (dy=-1: A[g+1] x side[g],
// g = 0..62, plus h=0 boundary A[0] x side[0] in wave 0).
// Regs ~250 (80 AGPR acc + 144 VGPR frags + addr) -> launch_bounds(256,2):
// 2 waves/SIMD, 2 blocks/CU (R4 showed 1 wave/SIMD exposes all latency).
__global__ __launch_bounds__(256, 2) void cofe_gemm(const unsigned short* __restrict__ xb,
                                                    const unsigned short* __restrict__ xbm,
                                                    const unsigned short* __restrict__ xbp,
                                                    float* __restrict__ out,
                                                    float* __restrict__ norms) {
    constexpr int RW = 16;
    int blk  = blockIdx.x;
    int work = (blk & 7) * 72 + (blk >> 3);     // XCD swizzle
    int b = work / 36;
    int t = work % 36;
    int cbA = t / 6, cbB = t % 6;
    int c0 = cbA * 32, d0 = cbB * 32;

    int wv   = threadIdx.x >> 6;                // 0..3
    int lane = threadIdx.x & 63;
    int lr   = lane & 31;
    int lo   = lane >> 5;
    int laneoff = lo * 32 + lr;                 // short8 units

    const short8* A8  = (const short8*)xb  + (size_t)(b * 6 + cbA) * 16384;
    const short8* U8  = (const short8*)xb  + (size_t)(b * 6 + cbB) * 16384;
    const short8* Um8 = (const short8*)xbm + (size_t)(b * 6 + cbB) * 16384;
    const short8* Up8 = (const short8*)xbp + (size_t)(b * 6 + cbB) * 16384;

    floatx16 acc[5];
    #pragma unroll
    for (int o = 0; o < 5; ++o)
        #pragma unroll
        for (int e = 0; e < 16; ++e)
            acc[o][e] = 0.0f;

    int h0 = wv * RW;

    short8 A[3][4];                 // A rows: rotate (g, g+1, g+2)
    short8 U[2][4], Um[2][4], Up[2][4];   // B variants: ping-pong

    #pragma unroll
    for (int s = 0; s < 4; ++s) {
        U[0][s]  = U8 [(8 * h0 + 2 * s) * 32 + laneoff];
        Um[0][s] = Um8[(8 * h0 + 2 * s) * 32 + laneoff];
        Up[0][s] = Up8[(8 * h0 + 2 * s) * 32 + laneoff];
        A[0][s]  = A8 [(8 * h0 + 2 * s) * 32 + laneoff];
        A[1][s]  = A8 [(8 * (h0 + 1) + 2 * s) * 32 + laneoff];
    }

    // h = 0 boundary: dy=-1 offsets pair center row 0 with clamped side row 0
    if (h0 == 0) {
        #pragma unroll
        for (int s = 0; s < 4; ++s) {
            acc[0] = __builtin_amdgcn_mfma_f32_32x32x16_bf16(A[0][s], Um[0][s], acc[0], 0, 0, 0);
            acc[1] = __builtin_amdgcn_mfma_f32_32x32x16_bf16(A[0][s], U[0][s],  acc[1], 0, 0, 0);
            acc[2] = __builtin_amdgcn_mfma_f32_32x32x16_bf16(A[0][s], Up[0][s], acc[2], 0, 0, 0);
        }
    }

    #pragma unroll
    for (int r = 0; r < RW; ++r) {
        int g  = h0 + r;
        const int cu = r & 1, nx = (r + 1) & 1;
        const int ia = r % 3, ib = (r + 1) % 3, ic = (r + 2) % 3;
        int ga = (g + 2 < 64) ? g + 2 : 63;     // A prefetch row (clamped dummy at tail)
        int gu = (g + 1 < 64) ? g + 1 : 63;     // B prefetch row
        #pragma unroll
        for (int s = 0; s < 4; ++s) {
            A[ic][s]  = A8 [(8 * ga + 2 * s) * 32 + laneoff];
            U[nx][s]  = U8 [(8 * gu + 2 * s) * 32 + laneoff];
            Um[nx][s] = Um8[(8 * gu + 2 * s) * 32 + laneoff];
            Up[nx][s] = Up8[(8 * gu + 2 * s) * 32 + laneoff];

            // OFFSETS: 0:(-1,-1) 1:(-1,0) 2:(-1,1) 3:(0,-1) 4:(0,0)
            acc[4] = __builtin_amdgcn_mfma_f32_32x32x16_bf16(A[ia][s], U[cu][s],  acc[4], 0, 0, 0);
            acc[3] = __builtin_amdgcn_mfma_f32_32x32x16_bf16(A[ia][s], Um[cu][s], acc[3], 0, 0, 0);
            if (r + 1 < RW || g < 63) {         // dy=-1 sum runs g = 0..62
                acc[1] = __builtin_amdgcn_mfma_f32_32x32x16_bf16(A[ib][s], U[cu][s],  acc[1], 0, 0, 0);
                acc[0] = __builtin_amdgcn_mfma_f32_32x32x16_bf16(A[ib][s], Um[cu][s], acc[0], 0, 0, 0);
                acc[2] = __builtin_amdgcn_mfma_f32_32x32x16_bf16(A[ib][s], Up[cu][s], acc[2], 0, 0, 0);
            }
        }
    }

    // ---- epilogue: LDS-reduce 4 wave partials, store, one norm atomic per offset ----
    // (verified in R4)
    __shared__ float red[4096];   // 16 KB
    __shared__ float wsum[4];
    float4* red4 = (float4*)red;
    size_t obase = (size_t)b * NO * (C_CH * C_CH);
    int tt = threadIdx.x;

    for (int o = 0; o < 5; ++o) {
        __syncthreads();
        #pragma unroll
        for (int reg = 0; reg < 16; ++reg) {
            int row = (reg & 3) + 8 * (reg >> 2) + 4 * lo;  // C/D layout (m74/m101)
            red[wv * 1024 + row * 32 + lr] = acc[o][reg];
        }
        __syncthreads();
        float4 sv = red4[tt];
        #pragma unroll
        for (int seg = 1; seg < 4; ++seg) {
            float4 v = red4[seg * 256 + tt];
            sv.x += v.x; sv.y += v.y; sv.z += v.z; sv.w += v.w;
        }
        int row = tt >> 3;
        int col = (tt & 7) * 4;
        float* op = out + obase + (size_t)o * (C_CH * C_CH)
                  + (size_t)(c0 + row) * C_CH + d0 + col;
        *(float4*)op = sv;

        float ss = sv.x * sv.x + sv.y * sv.y + sv.z * sv.z + sv.w * sv.w;
        #pragma unroll
        for (int off = 32; off; off >>= 1) ss += __shfl_down(ss, off, 64);
        if (lane == 0) wsum[wv] = ss;
        __syncthreads();
        if (tt == 0) atomicAdd(&norms[b * NO + o],
                               wsum[0] + wsum[1] + wsum[2] + wsum[3]);
    }
}

// ---------------- Kernel 3: scale by 1/norm ----------------
__global__ __launch_bounds__(256) void scale_kernel(float* __restrict__ out,
                                                    const float* __restrict__ norms) {
    int g  = blockIdx.x * 256 + threadIdx.x;    // float4 index, 737,280 total
    int bo = blockIdx.x / 36;                   // 9216 float4 per (b,o)
    float s = norms[bo];
    float inv = 1.0f / fmaxf(sqrtf(s), 1e-12f);
    float4 v = ((const float4*)out)[g];
    v.x *= inv; v.y *= inv; v.z *= inv; v.w *= inv;
    ((float4*)out)[g] = v;
}

extern "C" void kernel_launch(void* const* d_in, const int* in_sizes, int n_in,
                              void* d_out, int out_size, void* d_ws, size_t ws_size,
                              hipStream_t stream) {
    const float* x = (const float*)d_in[0];
    float* out = (float*)d_out;
    float* norms = (float*)d_ws;                                       // 80 floats (+pad)
    unsigned short* xb  = (unsigned short*)((char*)d_ws + 512);        // center panel
    unsigned short* xbm = (unsigned short*)((char*)d_ws + 512 + (size_t)PANEL);      // w-1 panel
    unsigned short* xbp = (unsigned short*)((char*)d_ws + 512 + 2 * (size_t)PANEL);  // w+1 panel

    convert_kernel<<<6144, 256, 0, stream>>>(x, xb, xbm, xbp, norms);
    cofe_gemm<<<576, 256, 0, stream>>>(xb, xbm, xbp, out, norms);
    scale_kernel<<<2880, 256, 0, stream>>>(out, norms);
}